// Round 2
// baseline (128.729 us; speedup 1.0000x reference)
//
#include <hip/hip_runtime.h>
#include <stdint.h>

#define M52 0xFFFFFFFFFFFFFULL

// One thread per row; no cross-lane ops. Each thread:
//   - loads its 64-float A row and B row as 16+16 dwordx4 (independent, deep MLP)
//   - packs to position-indexed uint64 via bit-29 test (1.0f == 0x3F800000)
//   - brev -> IEEE-754 binary64 pattern; exact integer emulation of the circuit
//   - unpacks result and stores 16 dwordx4
__global__ __launch_bounds__(256) void fp64div_kernel(
    const uint4* __restrict__ A, const uint4* __restrict__ B,
    uint4* __restrict__ out, int n_rows)
{
    const int row = blockIdx.x * blockDim.x + threadIdx.x;
    if (row >= n_rows) return;

    const uint4* ap = A + (size_t)row * 16;
    const uint4* bp = B + (size_t)row * 16;

    uint4 va[16], vb[16];
    #pragma unroll
    for (int j = 0; j < 16; ++j) va[j] = ap[j];
    #pragma unroll
    for (int j = 0; j < 16; ++j) vb[j] = bp[j];

    // ---- pack: bit e (position-indexed, e = 4j+c) = (row[e] != 0) ----
    uint32_t alo = 0u, ahi = 0u, blo = 0u, bhi = 0u;
    #pragma unroll
    for (int j = 0; j < 8; ++j) {
        alo |= ((va[j].x >> 29) & 1u) << (4 * j + 0);
        alo |= ((va[j].y >> 29) & 1u) << (4 * j + 1);
        alo |= ((va[j].z >> 29) & 1u) << (4 * j + 2);
        alo |= ((va[j].w >> 29) & 1u) << (4 * j + 3);
        blo |= ((vb[j].x >> 29) & 1u) << (4 * j + 0);
        blo |= ((vb[j].y >> 29) & 1u) << (4 * j + 1);
        blo |= ((vb[j].z >> 29) & 1u) << (4 * j + 2);
        blo |= ((vb[j].w >> 29) & 1u) << (4 * j + 3);
    }
    #pragma unroll
    for (int j = 8; j < 16; ++j) {
        ahi |= ((va[j].x >> 29) & 1u) << (4 * j - 32);
        ahi |= ((va[j].y >> 29) & 1u) << (4 * j - 31);
        ahi |= ((va[j].z >> 29) & 1u) << (4 * j - 30);
        ahi |= ((va[j].w >> 29) & 1u) << (4 * j - 29);
        bhi |= ((vb[j].x >> 29) & 1u) << (4 * j - 32);
        bhi |= ((vb[j].y >> 29) & 1u) << (4 * j - 31);
        bhi |= ((vb[j].z >> 29) & 1u) << (4 * j - 30);
        bhi |= ((vb[j].w >> 29) & 1u) << (4 * j - 29);
    }

    // Bit-reversed position-indexed word == IEEE-754 binary64 bit pattern.
    const uint64_t av = __brevll(((uint64_t)ahi << 32) | alo);
    const uint64_t bv = __brevll(((uint64_t)bhi << 32) | blo);

    const uint32_t sa = (uint32_t)(av >> 63), sb = (uint32_t)(bv >> 63);
    const uint32_t s_out = sa ^ sb;
    const uint32_t Ea = (uint32_t)(av >> 52) & 0x7FFu;
    const uint32_t Eb = (uint32_t)(bv >> 52) & 0x7FFu;
    const uint64_t Ma = av & M52;
    const uint64_t Mb = bv & M52;

    const bool ea_all1 = (Ea == 0x7FFu), eb_all1 = (Eb == 0x7FFu);
    const bool ea_zero = (Ea == 0u),     eb_zero = (Eb == 0u);
    const bool ma_zero = (Ma == 0ull),   mb_zero = (Mb == 0ull);
    const bool a_zero = ea_zero && ma_zero, b_zero = eb_zero && mb_zero;
    const bool a_inf  = ea_all1 && ma_zero, b_inf  = eb_all1 && mb_zero;
    const bool a_nan  = ea_all1 && !ma_zero, b_nan = eb_all1 && !mb_zero;

    const bool r_nan  = a_nan || b_nan || (a_zero && b_zero) || (a_inf && b_inf);
    const bool r_inf  = (!a_zero && b_zero) || (a_inf && !b_inf);
    const bool r_zero = (a_zero && !b_zero) || (!a_inf && b_inf);

    // 13-bit circuit exponent arithmetic (mod 8192)
    const uint32_t exp13 = (Ea - Eb + 1023u) & 0x1FFFu;

    // 57-step restoring division on 55-bit values (R < 2D invariant keeps
    // everything < 2^55 so the circuit's 55-bit truncation is a no-op).
    uint64_t R = (1ULL << 53) | (Ma << 1);
    const uint64_t D = (1ULL << 53) | (Mb << 1);
    uint64_t Q = 0;
    #pragma unroll
    for (int i = 0; i < 56; ++i) {
        const bool ge = (R >= D);
        const uint64_t t = R - D;
        R = ge ? t : R;
        Q = (Q << 1) | (ge ? 1u : 0u);
        R <<= 1;
    }
    {   // final step, no shift
        const bool ge = (R >= D);
        const uint64_t t = R - D;
        R = ge ? t : R;
        Q = (Q << 1) | (ge ? 1u : 0u);
    }

    const uint32_t q0 = (uint32_t)(Q >> 56) & 1u;
    const uint32_t rem_nz = (R != 0ull) ? 1u : 0u;

    const uint64_t mant52 = q0 ? ((Q >> 4) & M52) : ((Q >> 3) & M52);
    const uint32_t rbit   = q0 ? ((uint32_t)(Q >> 3) & 1u) : ((uint32_t)(Q >> 2) & 1u);
    const uint32_t sticky = (q0 ? (((Q & 7ull) != 0ull) ? 1u : 0u)
                                : (((Q & 3ull) != 0ull) ? 1u : 0u)) | rem_nz;
    const uint32_t exp_f  = q0 ? exp13 : ((exp13 - 1u) & 0x1FFFu);

    const uint32_t lsb = (uint32_t)mant52 & 1u;
    const uint32_t rup = rbit & (sticky | lsb);
    // circuit quirk: 53-bit adder carry-out is identically 0, so mantissa
    // overflow wraps to 0 WITHOUT exponent bump.
    const uint64_t mant_final = (mant52 + rup) & M52;

    const uint32_t exp11   = exp_f & 0x7FFu;
    const bool overflow  = (exp_f >> 11) != 0u;            // bits 11|12
    const bool underflow = (((exp_f >> 12) & 1u) != 0u) || (exp_f == 0u);

    uint64_t res = ((uint64_t)s_out << 63) | ((uint64_t)exp11 << 52) | mant_final;
    const uint64_t zero_v = ((uint64_t)s_out << 63);
    const uint64_t inf_v  = zero_v | (0x7FFULL << 52);
    const uint64_t nan_v  = inf_v | (1ULL << 51);

    if (r_nan)          res = nan_v;
    else if (r_inf)     res = inf_v;
    else if (r_zero)    res = zero_v;
    else if (overflow)  res = inf_v;
    else if (underflow) res = zero_v;

    const uint64_t ow = __brevll(res);   // back to position-indexed bits
    const uint32_t owlo = (uint32_t)ow;
    const uint32_t owhi = (uint32_t)(ow >> 32);

    // ---- unpack + store: float e = bit e ? 1.0f : 0.0f, 16B per store ----
    uint4* op = out + (size_t)row * 16;
    #pragma unroll
    for (int j = 0; j < 16; ++j) {
        const uint32_t w = (j < 8) ? owlo : owhi;
        const int base = (4 * j) & 31;
        uint4 o;
        o.x = 0x3F800000u & (uint32_t)((int32_t)(w << (31 - (base + 0))) >> 31);
        o.y = 0x3F800000u & (uint32_t)((int32_t)(w << (31 - (base + 1))) >> 31);
        o.z = 0x3F800000u & (uint32_t)((int32_t)(w << (31 - (base + 2))) >> 31);
        o.w = 0x3F800000u & (uint32_t)((int32_t)(w << (31 - (base + 3))) >> 31);
        op[j] = o;
    }
}

extern "C" void kernel_launch(void* const* d_in, const int* in_sizes, int n_in,
                              void* d_out, int out_size, void* d_ws, size_t ws_size,
                              hipStream_t stream) {
    const uint4* A = (const uint4*)d_in[0];
    const uint4* B = (const uint4*)d_in[1];
    uint4* out = (uint4*)d_out;
    const int n_rows = in_sizes[0] / 64;
    const int threads = 256;
    const int blocks = (n_rows + threads - 1) / threads;
    fp64div_kernel<<<blocks, threads, 0, stream>>>(A, B, out, n_rows);
}

// Round 3
// 99.879 us; speedup vs baseline: 1.2889x; 1.2889x over previous
//
#include <hip/hip_runtime.h>
#include <stdint.h>

#define M52 0xFFFFFFFFFFFFFULL

__device__ __forceinline__ uint64_t shfl64(uint64_t x, int src) {
    int lo = __shfl((int)(uint32_t)x, src, 64);
    int hi = __shfl((int)(uint32_t)(x >> 32), src, 64);
    return ((uint64_t)(uint32_t)hi << 32) | (uint64_t)(uint32_t)lo;
}

// One thread per row; wave (64 lanes) cooperates on 64 consecutive rows.
// Lane l always touches element l -> every global access is a fully-coalesced
// 256 B wave transaction. Transpose float-row -> packed uint64 via __ballot.
// Loads are hoisted in 32-deep batches so >=32 dword loads stay in flight per
// wave (MLP fix vs R1's 16-deep batches). VGPRs are free: only 2 waves/SIMD
// possible (2048 waves problem-wide), so __launch_bounds__(256,2) allows 256.
__global__ __launch_bounds__(256, 2) void fp64div_kernel(
    const float* __restrict__ A, const float* __restrict__ B,
    float* __restrict__ out, int n_rows)
{
    const int tid  = blockIdx.x * blockDim.x + threadIdx.x;
    const int lane = threadIdx.x & 63;
    const int wave_base = tid & ~63;
    if (wave_base >= n_rows) return;           // n_rows % 64 == 0

    const float* Ap = A + (size_t)wave_base * 64 + lane;
    const float* Bp = B + (size_t)wave_base * 64 + lane;

    // ---- load: 4 batches of 32 coalesced dword loads, software-pipelined
    //      against the ballot-pack so the memory pipe never drains ----
    float fa0[32], fa1[32], fb0[32], fb1[32];
    uint64_t my_a = 0, my_b = 0;

    #pragma unroll
    for (int r = 0; r < 32; ++r) fa0[r] = Ap[(size_t)r * 64];
    #pragma unroll
    for (int r = 0; r < 32; ++r) fb0[r] = Bp[(size_t)r * 64];

    // pack A[0:32) while B[0:32) is still in flight
    #pragma unroll
    for (int r = 0; r < 32; ++r) {
        uint64_t m = __ballot(fa0[r] != 0.0f);
        if (lane == r) my_a = m;
    }
    #pragma unroll
    for (int r = 0; r < 32; ++r) fa1[r] = Ap[(size_t)(r + 32) * 64];

    #pragma unroll
    for (int r = 0; r < 32; ++r) {
        uint64_t m = __ballot(fb0[r] != 0.0f);
        if (lane == r) my_b = m;
    }
    #pragma unroll
    for (int r = 0; r < 32; ++r) fb1[r] = Bp[(size_t)(r + 32) * 64];

    #pragma unroll
    for (int r = 0; r < 32; ++r) {
        uint64_t m = __ballot(fa1[r] != 0.0f);
        if (lane == r + 32) my_a = m;
    }
    #pragma unroll
    for (int r = 0; r < 32; ++r) {
        uint64_t m = __ballot(fb1[r] != 0.0f);
        if (lane == r + 32) my_b = m;
    }

    // Bit-reversed position-indexed word == IEEE-754 binary64 bit pattern.
    const uint64_t av = __brevll(my_a);
    const uint64_t bv = __brevll(my_b);

    const uint32_t sa = (uint32_t)(av >> 63), sb = (uint32_t)(bv >> 63);
    const uint32_t s_out = sa ^ sb;
    const uint32_t Ea = (uint32_t)(av >> 52) & 0x7FFu;
    const uint32_t Eb = (uint32_t)(bv >> 52) & 0x7FFu;
    const uint64_t Ma = av & M52;
    const uint64_t Mb = bv & M52;

    const bool ea_all1 = (Ea == 0x7FFu), eb_all1 = (Eb == 0x7FFu);
    const bool ea_zero = (Ea == 0u),     eb_zero = (Eb == 0u);
    const bool ma_zero = (Ma == 0ull),   mb_zero = (Mb == 0ull);
    const bool a_zero = ea_zero && ma_zero, b_zero = eb_zero && mb_zero;
    const bool a_inf  = ea_all1 && ma_zero, b_inf  = eb_all1 && mb_zero;
    const bool a_nan  = ea_all1 && !ma_zero, b_nan = eb_all1 && !mb_zero;

    const bool r_nan  = a_nan || b_nan || (a_zero && b_zero) || (a_inf && b_inf);
    const bool r_inf  = (!a_zero && b_zero) || (a_inf && !b_inf);
    const bool r_zero = (a_zero && !b_zero) || (!a_inf && b_inf);

    // 13-bit circuit exponent arithmetic (mod 8192)
    const uint32_t exp13 = (Ea - Eb + 1023u) & 0x1FFFu;

    // 57-step restoring division on 55-bit values (R < 2D invariant keeps
    // everything < 2^55 so the circuit's 55-bit truncation is a no-op).
    uint64_t R = (1ULL << 53) | (Ma << 1);
    const uint64_t D = (1ULL << 53) | (Mb << 1);
    uint64_t Q = 0;
    #pragma unroll
    for (int i = 0; i < 56; ++i) {
        const bool ge = (R >= D);
        const uint64_t t = R - D;
        R = ge ? t : R;
        Q = (Q << 1) | (ge ? 1u : 0u);
        R <<= 1;
    }
    {   // final step, no shift
        const bool ge = (R >= D);
        const uint64_t t = R - D;
        R = ge ? t : R;
        Q = (Q << 1) | (ge ? 1u : 0u);
    }

    const uint32_t q0 = (uint32_t)(Q >> 56) & 1u;
    const uint32_t rem_nz = (R != 0ull) ? 1u : 0u;

    const uint64_t mant52 = q0 ? ((Q >> 4) & M52) : ((Q >> 3) & M52);
    const uint32_t rbit   = q0 ? ((uint32_t)(Q >> 3) & 1u) : ((uint32_t)(Q >> 2) & 1u);
    const uint32_t sticky = (q0 ? (((Q & 7ull) != 0ull) ? 1u : 0u)
                                : (((Q & 3ull) != 0ull) ? 1u : 0u)) | rem_nz;
    const uint32_t exp_f  = q0 ? exp13 : ((exp13 - 1u) & 0x1FFFu);

    const uint32_t lsb = (uint32_t)mant52 & 1u;
    const uint32_t rup = rbit & (sticky | lsb);
    // circuit quirk: 53-bit adder carry-out is identically 0, so mantissa
    // overflow wraps to 0 WITHOUT exponent bump.
    const uint64_t mant_final = (mant52 + rup) & M52;

    const uint32_t exp11   = exp_f & 0x7FFu;
    const bool overflow  = (exp_f >> 11) != 0u;            // bits 11|12
    const bool underflow = (((exp_f >> 12) & 1u) != 0u) || (exp_f == 0u);

    uint64_t res = ((uint64_t)s_out << 63) | ((uint64_t)exp11 << 52) | mant_final;
    const uint64_t zero_v = ((uint64_t)s_out << 63);
    const uint64_t inf_v  = zero_v | (0x7FFULL << 52);
    const uint64_t nan_v  = inf_v | (1ULL << 51);

    if (r_nan)          res = nan_v;
    else if (r_inf)     res = inf_v;
    else if (r_zero)    res = zero_v;
    else if (overflow)  res = inf_v;
    else if (underflow) res = zero_v;

    const uint64_t out_word = __brevll(res);   // back to position-indexed bits

    // ---- store: lane l writes element l of each row; 64 independent
    //      coalesced 256 B wave stores ----
    float* Op = out + (size_t)wave_base * 64 + lane;
    #pragma unroll
    for (int r = 0; r < 64; ++r) {
        const uint64_t w = shfl64(out_word, r);
        Op[(size_t)r * 64] = (float)((uint32_t)(w >> lane) & 1u);
    }
}

extern "C" void kernel_launch(void* const* d_in, const int* in_sizes, int n_in,
                              void* d_out, int out_size, void* d_ws, size_t ws_size,
                              hipStream_t stream) {
    const float* A = (const float*)d_in[0];
    const float* B = (const float*)d_in[1];
    float* out = (float*)d_out;
    const int n_rows = in_sizes[0] / 64;
    const int threads = 256;
    const int blocks = (n_rows + threads - 1) / threads;
    fp64div_kernel<<<blocks, threads, 0, stream>>>(A, B, out, n_rows);
}